// Round 4
// baseline (697.640 us; speedup 1.0000x reference)
//
#include <hip/hip_runtime.h>

#define NN 100000
#define NE 1200000
#define NG 2000
#define IND 36
#define HIDD 64
#define BN_EPS 1e-5f

// ---------------- CSR build ----------------

__global__ void k_indeg(const int* __restrict__ dst, int* __restrict__ indeg) {
    int e = blockIdx.x * 256 + threadIdx.x;
    if (e < NE) atomicAdd(&indeg[dst[e]], 1);
}

__global__ void k_dinv(const int* __restrict__ indeg, float* __restrict__ dinv) {
    int i = blockIdx.x * 256 + threadIdx.x;
    if (i < NN) dinv[i] = 1.0f / sqrtf((float)indeg[i] + 1.0f);
}

__global__ void k_scan1(const int* __restrict__ indeg, int* __restrict__ bsum) {
    __shared__ int sh[256];
    int i = blockIdx.x * 256 + threadIdx.x;
    sh[threadIdx.x] = (i < NN) ? indeg[i] : 0;
    __syncthreads();
    for (int s = 128; s > 0; s >>= 1) {
        if (threadIdx.x < s) sh[threadIdx.x] += sh[threadIdx.x + s];
        __syncthreads();
    }
    if (threadIdx.x == 0) bsum[blockIdx.x] = sh[0];
}

__global__ void k_scan2(int* bsum, int nb) {
    if (threadIdx.x == 0) {
        int acc = 0;
        for (int i = 0; i < nb; i++) { int v = bsum[i]; bsum[i] = acc; acc += v; }
    }
}

__global__ void k_scan3(const int* __restrict__ indeg, const int* __restrict__ bsum,
                        int* __restrict__ rowstart) {
    __shared__ int sh[256];
    int i = blockIdx.x * 256 + threadIdx.x;
    int v = (i < NN) ? indeg[i] : 0;
    sh[threadIdx.x] = v;
    __syncthreads();
    for (int s = 1; s < 256; s <<= 1) {
        int t = (threadIdx.x >= s) ? sh[threadIdx.x - s] : 0;
        __syncthreads();
        sh[threadIdx.x] += t;
        __syncthreads();
    }
    if (i < NN) rowstart[i] = bsum[blockIdx.x] + sh[threadIdx.x] - v;  // exclusive
}

__global__ void k_fill(const int* __restrict__ src, const int* __restrict__ dst,
                       const int* __restrict__ rowstart, int* __restrict__ cursor,
                       const float* __restrict__ dinv,
                       int* __restrict__ csr_src, float* __restrict__ csr_coef) {
    int e = blockIdx.x * 256 + threadIdx.x;
    if (e < NE) {
        int s = src[e], d = dst[e];
        int p = rowstart[d] + atomicAdd(&cursor[d], 1);
        csr_src[p]  = s;
        csr_coef[p] = dinv[s] * dinv[d];
    }
}

// ---------------- dense: out[N,64] = x[N,K] @ W[K,64] ----------------

template<int K>
__global__ void k_dense(const float* __restrict__ x, const float* __restrict__ W,
                        float* __restrict__ out) {
    __shared__ float Ws[K * 64];
    __shared__ float xs[4 * K];
    int tid = threadIdx.x;
    for (int i = tid; i < K * 64; i += 256) Ws[i] = W[i];
    int n0 = blockIdx.x * 4;
    for (int i = tid; i < 4 * K; i += 256) xs[i] = x[n0 * K + i];
    __syncthreads();
    int nl = tid >> 6, j = tid & 63;
    const float* xr = &xs[nl * K];
    float acc = 0.0f;
#pragma unroll
    for (int k = 0; k < K; k++) acc = fmaf(xr[k], Ws[k * 64 + j], acc);
    out[(size_t)(n0 + nl) * 64 + j] = acc;
}

// ---------------- gather (message passing + self loop + bias + relu) ----------------

__global__ void k_gather(const float* __restrict__ hlin, const int* __restrict__ rowstart,
                         const int* __restrict__ indeg, const int* __restrict__ csr_src,
                         const float* __restrict__ csr_coef, const float* __restrict__ dinv,
                         const float* __restrict__ bias, float* __restrict__ out) {
    int node = blockIdx.x * 4 + (threadIdx.x >> 6);
    int lane = threadIdx.x & 63;
    if (node >= NN) return;
    float di = dinv[node];
    float acc = hlin[(size_t)node * 64 + lane] * (di * di);
    int start = rowstart[node];
    int len   = indeg[node];
    for (int k = 0; k < len; k++) {
        int   s = csr_src[start + k];
        float c = csr_coef[start + k];
        acc = fmaf(hlin[(size_t)s * 64 + lane], c, acc);
    }
    out[(size_t)node * 64 + lane] = fmaxf(acc + bias[lane], 0.0f);
}

// ---------------- pooling (batch is sorted: run-accumulate in registers) ----------------

__global__ void k_pool(const float* __restrict__ h, const int* __restrict__ batch,
                       float* __restrict__ msum, float* __restrict__ mmax,
                       float* __restrict__ cnt) {
    int lane = threadIdx.x & 63;
    int wave = threadIdx.x >> 6;
    int start = blockIdx.x * 256 + wave * 64;
    if (start >= NN) return;
    int end = min(start + 64, NN);
    int cur = batch[start];
    float s = 0.0f, m = 0.0f;
    int run = 0;
    for (int n = start; n < end; n++) {
        int g = batch[n];
        if (g != cur) {
            atomicAdd(&msum[cur * 64 + lane], s);
            atomicMax((int*)&mmax[cur * 64 + lane], __float_as_int(m));
            if (lane == 0) atomicAdd(&cnt[cur], (float)run);
            s = 0.0f; m = 0.0f; run = 0; cur = g;
        }
        float v = h[(size_t)n * 64 + lane];
        s += v;
        m = fmaxf(m, v);
        run++;
    }
    atomicAdd(&msum[cur * 64 + lane], s);
    atomicMax((int*)&mmax[cur * 64 + lane], __float_as_int(m));
    if (lane == 0) atomicAdd(&cnt[cur], (float)run);
}

// ---------------- classifier head ----------------

__global__ void k_cls(const float* __restrict__ msum, const float* __restrict__ mmax,
                      const float* __restrict__ cnt,
                      const float* __restrict__ cw1, const float* __restrict__ cb1,
                      const float* __restrict__ g1,  const float* __restrict__ be1,
                      const float* __restrict__ cw2, const float* __restrict__ cb2,
                      const float* __restrict__ g2,  const float* __restrict__ be2,
                      const float* __restrict__ cw3, const float* __restrict__ cb3,
                      float* __restrict__ out) {
    __shared__ float emb[128];
    __shared__ float z1[64];
    __shared__ float z2[32];
    int g = blockIdx.x;
    int t = threadIdx.x;
    float invc = 1.0f / fmaxf(cnt[g], 1.0f);
    emb[t]      = msum[g * 64 + t] * invc;
    emb[64 + t] = mmax[g * 64 + t];
    __syncthreads();
    float acc = cb1[t];
#pragma unroll
    for (int k = 0; k < 128; k++) acc = fmaf(emb[k], cw1[k * 64 + t], acc);
    acc = acc * (g1[t] / sqrtf(1.0f + BN_EPS)) + be1[t];
    z1[t] = fmaxf(acc, 0.0f);
    __syncthreads();
    if (t < 32) {
        float a = cb2[t];
#pragma unroll
        for (int k = 0; k < 64; k++) a = fmaf(z1[k], cw2[k * 32 + t], a);
        a = a * (g2[t] / sqrtf(1.0f + BN_EPS)) + be2[t];
        z2[t] = fmaxf(a, 0.0f);
    }
    __syncthreads();
    if (t < 5) {
        float a = cb3[t];
#pragma unroll
        for (int k = 0; k < 32; k++) a = fmaf(z2[k], cw3[k * 5 + t], a);
        out[g * 5 + t] = a;
    }
}

// ---------------- launch ----------------

extern "C" void kernel_launch(void* const* d_in, const int* in_sizes, int n_in,
                              void* d_out, int out_size, void* d_ws, size_t ws_size,
                              hipStream_t stream) {
    const float* x     = (const float*)d_in[0];
    const int*   ei    = (const int*)d_in[1];
    const int*   src   = ei;
    const int*   dst   = ei + NE;
    const int*   batch = (const int*)d_in[2];
    const float* W1  = (const float*)d_in[3];
    const float* b1  = (const float*)d_in[4];
    const float* W2  = (const float*)d_in[5];
    const float* b2  = (const float*)d_in[6];
    const float* W3  = (const float*)d_in[7];
    const float* b3  = (const float*)d_in[8];
    const float* cw1 = (const float*)d_in[9];
    const float* cb1 = (const float*)d_in[10];
    const float* g1  = (const float*)d_in[11];
    const float* be1 = (const float*)d_in[12];
    const float* cw2 = (const float*)d_in[13];
    const float* cb2 = (const float*)d_in[14];
    const float* g2  = (const float*)d_in[15];
    const float* be2 = (const float*)d_in[16];
    const float* cw3 = (const float*)d_in[17];
    const float* cb3 = (const float*)d_in[18];
    float* out = (float*)d_out;

    char* ws = (char*)d_ws;
    size_t off = 0;
    auto alloc = [&](size_t bytes) {
        off = (off + 255) & ~(size_t)255;
        void* p = ws + off;
        off += bytes;
        return p;
    };

    int*   indeg    = (int*)alloc(NN * 4);
    float* dinv     = (float*)alloc(NN * 4);
    int*   rowstart = (int*)alloc(NN * 4);
    int*   cursor   = (int*)alloc(NN * 4);
    int*   bsum     = (int*)alloc(512 * 4);
    int*   csr_src  = (int*)alloc((size_t)NE * 4);
    float* csr_coef = (float*)alloc((size_t)NE * 4);
    float* A        = (float*)alloc((size_t)NN * 64 * 4);
    float* B        = (float*)alloc((size_t)NN * 64 * 4);
    float* msum     = (float*)alloc((size_t)NG * 64 * 4);
    float* mmax     = (float*)alloc((size_t)NG * 64 * 4);
    float* cnt      = (float*)alloc((size_t)NG * 4);

    hipMemsetAsync(indeg,  0, NN * 4, stream);
    hipMemsetAsync(cursor, 0, NN * 4, stream);
    hipMemsetAsync(msum,   0, (size_t)NG * 64 * 4, stream);
    hipMemsetAsync(mmax,   0, (size_t)NG * 64 * 4, stream);
    hipMemsetAsync(cnt,    0, (size_t)NG * 4, stream);

    const int NB_E = (NE + 255) / 256;    // 4688
    const int NB_N = (NN + 255) / 256;    // 391

    k_indeg<<<NB_E, 256, 0, stream>>>(dst, indeg);
    k_dinv <<<NB_N, 256, 0, stream>>>(indeg, dinv);
    k_scan1<<<NB_N, 256, 0, stream>>>(indeg, bsum);
    k_scan2<<<1, 64, 0, stream>>>(bsum, NB_N);
    k_scan3<<<NB_N, 256, 0, stream>>>(indeg, bsum, rowstart);
    k_fill <<<NB_E, 256, 0, stream>>>(src, dst, rowstart, cursor, dinv, csr_src, csr_coef);

    const int NB_D = NN / 4;  // 25000

    // layer 1
    k_dense<IND><<<NB_D, 256, 0, stream>>>(x, W1, A);
    k_gather<<<NB_D, 256, 0, stream>>>(A, rowstart, indeg, csr_src, csr_coef, dinv, b1, B);
    // layer 2
    k_dense<HIDD><<<NB_D, 256, 0, stream>>>(B, W2, A);
    k_gather<<<NB_D, 256, 0, stream>>>(A, rowstart, indeg, csr_src, csr_coef, dinv, b2, B);
    // layer 3
    k_dense<HIDD><<<NB_D, 256, 0, stream>>>(B, W3, A);
    k_gather<<<NB_D, 256, 0, stream>>>(A, rowstart, indeg, csr_src, csr_coef, dinv, b3, B);

    k_pool<<<NB_N, 256, 0, stream>>>(B, batch, msum, mmax, cnt);

    k_cls<<<NG, 64, 0, stream>>>(msum, mmax, cnt, cw1, cb1, g1, be1,
                                 cw2, cb2, g2, be2, cw3, cb3, out);
}

// Round 5
// 480.625 us; speedup vs baseline: 1.4515x; 1.4515x over previous
//
#include <hip/hip_runtime.h>

#define NN 100000
#define NE 1200000
#define NG 2000
#define IND 36
#define HIDD 64
#define BN_EPS 1e-5f

// ---------------- CSR build ----------------

__global__ void k_indeg(const int* __restrict__ dst, int* __restrict__ indeg) {
    int e = blockIdx.x * 256 + threadIdx.x;
    if (e < NE) atomicAdd(&indeg[dst[e]], 1);
}

// block-sum for scan + dinv (folded in: reads indeg anyway)
__global__ void k_scan1(const int* __restrict__ indeg, int* __restrict__ bsum,
                        float* __restrict__ dinv) {
    __shared__ int sh[256];
    int i = blockIdx.x * 256 + threadIdx.x;
    int v = (i < NN) ? indeg[i] : 0;
    if (i < NN) dinv[i] = rsqrtf((float)v + 1.0f);
    sh[threadIdx.x] = v;
    __syncthreads();
    for (int s = 128; s > 0; s >>= 1) {
        if (threadIdx.x < s) sh[threadIdx.x] += sh[threadIdx.x + s];
        __syncthreads();
    }
    if (threadIdx.x == 0) bsum[blockIdx.x] = sh[0];
}

// parallel exclusive scan of the 391 block sums (was a single-thread serial loop)
__global__ void k_scan2(int* __restrict__ bsum, int nb) {
    __shared__ int sh[512];
    int t = threadIdx.x;
    int v = (t < nb) ? bsum[t] : 0;
    sh[t] = v;
    __syncthreads();
    for (int s = 1; s < 512; s <<= 1) {
        int u = (t >= s) ? sh[t - s] : 0;
        __syncthreads();
        sh[t] += u;
        __syncthreads();
    }
    if (t < nb) bsum[t] = sh[t] - v;  // exclusive
}

__global__ void k_scan3(const int* __restrict__ indeg, const int* __restrict__ bsum,
                        int* __restrict__ rowstart) {
    __shared__ int sh[256];
    int i = blockIdx.x * 256 + threadIdx.x;
    int v = (i < NN) ? indeg[i] : 0;
    sh[threadIdx.x] = v;
    __syncthreads();
    for (int s = 1; s < 256; s <<= 1) {
        int t = (threadIdx.x >= s) ? sh[threadIdx.x - s] : 0;
        __syncthreads();
        sh[threadIdx.x] += t;
        __syncthreads();
    }
    if (i < NN) rowstart[i] = bsum[blockIdx.x] + sh[threadIdx.x] - v;  // exclusive
}

// packed CSR entry: .x = src node, .y = coef bits  (one 8B store / one 8B load per edge)
__global__ void k_fill(const int* __restrict__ src, const int* __restrict__ dst,
                       const int* __restrict__ rowstart, int* __restrict__ cursor,
                       const float* __restrict__ dinv, int2* __restrict__ csr) {
    int e = blockIdx.x * 256 + threadIdx.x;
    if (e < NE) {
        int s = src[e], d = dst[e];
        int p = rowstart[d] + atomicAdd(&cursor[d], 1);
        int2 ent;
        ent.x = s;
        ent.y = __float_as_int(dinv[s] * dinv[d]);
        csr[p] = ent;
    }
}

// ---------------- dense: out[N,64] = x[N,K] @ W[K,64] ----------------

template<int K>
__global__ void k_dense(const float* __restrict__ x, const float* __restrict__ W,
                        float* __restrict__ out) {
    __shared__ float Ws[K * 64];
    __shared__ float xs[4 * K];
    int tid = threadIdx.x;
    for (int i = tid; i < K * 64; i += 256) Ws[i] = W[i];
    int n0 = blockIdx.x * 4;
    for (int i = tid; i < 4 * K; i += 256) xs[i] = x[n0 * K + i];
    __syncthreads();
    int nl = tid >> 6, j = tid & 63;
    const float* xr = &xs[nl * K];
    float acc = 0.0f;
#pragma unroll
    for (int k = 0; k < K; k++) acc = fmaf(xr[k], Ws[k * 64 + j], acc);
    out[(size_t)(n0 + nl) * 64 + j] = acc;
}

// ---------------- gather: 4-wide MLP inner loop ----------------

__global__ void k_gather(const float* __restrict__ hlin, const int* __restrict__ rowstart,
                         const int* __restrict__ indeg, const int2* __restrict__ csr,
                         const float* __restrict__ dinv, const float* __restrict__ bias,
                         float* __restrict__ out) {
    int node = blockIdx.x * 4 + (threadIdx.x >> 6);
    int lane = threadIdx.x & 63;
    if (node >= NN) return;
    float di = dinv[node];
    float acc = hlin[(size_t)node * 64 + lane] * (di * di);
    int start = rowstart[node];
    int len   = indeg[node];
    int k = 0;
    // 4 independent row loads in flight per group -> 4x memory-level parallelism
    for (; k + 4 <= len; k += 4) {
        int2 e0 = csr[start + k + 0];
        int2 e1 = csr[start + k + 1];
        int2 e2 = csr[start + k + 2];
        int2 e3 = csr[start + k + 3];
        float v0 = hlin[(size_t)e0.x * 64 + lane];
        float v1 = hlin[(size_t)e1.x * 64 + lane];
        float v2 = hlin[(size_t)e2.x * 64 + lane];
        float v3 = hlin[(size_t)e3.x * 64 + lane];
        acc = fmaf(v0, __int_as_float(e0.y), acc);
        acc = fmaf(v1, __int_as_float(e1.y), acc);
        acc = fmaf(v2, __int_as_float(e2.y), acc);
        acc = fmaf(v3, __int_as_float(e3.y), acc);
    }
    for (; k < len; k++) {
        int2 e = csr[start + k];
        acc = fmaf(hlin[(size_t)e.x * 64 + lane], __int_as_float(e.y), acc);
    }
    out[(size_t)node * 64 + lane] = fmaxf(acc + bias[lane], 0.0f);
}

// ---------------- pooling (batch is sorted: run-accumulate in registers) ----------------

__global__ void k_pool(const float* __restrict__ h, const int* __restrict__ batch,
                       float* __restrict__ msum, float* __restrict__ mmax,
                       float* __restrict__ cnt) {
    int lane = threadIdx.x & 63;
    int wave = threadIdx.x >> 6;
    int start = blockIdx.x * 256 + wave * 64;
    if (start >= NN) return;
    int end = min(start + 64, NN);
    int cur = batch[start];
    float s = 0.0f, m = 0.0f;
    int run = 0;
    for (int n = start; n < end; n++) {
        int g = batch[n];
        if (g != cur) {
            atomicAdd(&msum[cur * 64 + lane], s);
            atomicMax((int*)&mmax[cur * 64 + lane], __float_as_int(m));
            if (lane == 0) atomicAdd(&cnt[cur], (float)run);
            s = 0.0f; m = 0.0f; run = 0; cur = g;
        }
        float v = h[(size_t)n * 64 + lane];
        s += v;
        m = fmaxf(m, v);
        run++;
    }
    atomicAdd(&msum[cur * 64 + lane], s);
    atomicMax((int*)&mmax[cur * 64 + lane], __float_as_int(m));
    if (lane == 0) atomicAdd(&cnt[cur], (float)run);
}

// ---------------- classifier head ----------------

__global__ void k_cls(const float* __restrict__ msum, const float* __restrict__ mmax,
                      const float* __restrict__ cnt,
                      const float* __restrict__ cw1, const float* __restrict__ cb1,
                      const float* __restrict__ g1,  const float* __restrict__ be1,
                      const float* __restrict__ cw2, const float* __restrict__ cb2,
                      const float* __restrict__ g2,  const float* __restrict__ be2,
                      const float* __restrict__ cw3, const float* __restrict__ cb3,
                      float* __restrict__ out) {
    __shared__ float emb[128];
    __shared__ float z1[64];
    __shared__ float z2[32];
    int g = blockIdx.x;
    int t = threadIdx.x;
    float invc = 1.0f / fmaxf(cnt[g], 1.0f);
    emb[t]      = msum[g * 64 + t] * invc;
    emb[64 + t] = mmax[g * 64 + t];
    __syncthreads();
    float acc = cb1[t];
#pragma unroll
    for (int k = 0; k < 128; k++) acc = fmaf(emb[k], cw1[k * 64 + t], acc);
    acc = acc * (g1[t] / sqrtf(1.0f + BN_EPS)) + be1[t];
    z1[t] = fmaxf(acc, 0.0f);
    __syncthreads();
    if (t < 32) {
        float a = cb2[t];
#pragma unroll
        for (int k = 0; k < 64; k++) a = fmaf(z1[k], cw2[k * 32 + t], a);
        a = a * (g2[t] / sqrtf(1.0f + BN_EPS)) + be2[t];
        z2[t] = fmaxf(a, 0.0f);
    }
    __syncthreads();
    if (t < 5) {
        float a = cb3[t];
#pragma unroll
        for (int k = 0; k < 32; k++) a = fmaf(z2[k], cw3[k * 5 + t], a);
        out[g * 5 + t] = a;
    }
}

// ---------------- launch ----------------

extern "C" void kernel_launch(void* const* d_in, const int* in_sizes, int n_in,
                              void* d_out, int out_size, void* d_ws, size_t ws_size,
                              hipStream_t stream) {
    const float* x     = (const float*)d_in[0];
    const int*   ei    = (const int*)d_in[1];
    const int*   src   = ei;
    const int*   dst   = ei + NE;
    const int*   batch = (const int*)d_in[2];
    const float* W1  = (const float*)d_in[3];
    const float* b1  = (const float*)d_in[4];
    const float* W2  = (const float*)d_in[5];
    const float* b2  = (const float*)d_in[6];
    const float* W3  = (const float*)d_in[7];
    const float* b3  = (const float*)d_in[8];
    const float* cw1 = (const float*)d_in[9];
    const float* cb1 = (const float*)d_in[10];
    const float* g1  = (const float*)d_in[11];
    const float* be1 = (const float*)d_in[12];
    const float* cw2 = (const float*)d_in[13];
    const float* cb2 = (const float*)d_in[14];
    const float* g2  = (const float*)d_in[15];
    const float* be2 = (const float*)d_in[16];
    const float* cw3 = (const float*)d_in[17];
    const float* cb3 = (const float*)d_in[18];
    float* out = (float*)d_out;

    char* ws = (char*)d_ws;
    size_t off = 0;
    auto alloc = [&](size_t bytes) {
        off = (off + 255) & ~(size_t)255;
        void* p = ws + off;
        off += bytes;
        return p;
    };

    int*   indeg    = (int*)alloc(NN * 4);
    float* dinv     = (float*)alloc(NN * 4);
    int*   rowstart = (int*)alloc(NN * 4);
    int*   cursor   = (int*)alloc(NN * 4);
    int*   bsum     = (int*)alloc(512 * 4);
    int2*  csr      = (int2*)alloc((size_t)NE * 8);
    float* A        = (float*)alloc((size_t)NN * 64 * 4);
    float* B        = (float*)alloc((size_t)NN * 64 * 4);
    float* msum     = (float*)alloc((size_t)NG * 64 * 4);
    float* mmax     = (float*)alloc((size_t)NG * 64 * 4);
    float* cnt      = (float*)alloc((size_t)NG * 4);

    hipMemsetAsync(indeg,  0, NN * 4, stream);
    hipMemsetAsync(cursor, 0, NN * 4, stream);
    hipMemsetAsync(msum,   0, (size_t)NG * 64 * 4, stream);
    hipMemsetAsync(mmax,   0, (size_t)NG * 64 * 4, stream);
    hipMemsetAsync(cnt,    0, (size_t)NG * 4, stream);

    const int NB_E = (NE + 255) / 256;    // 4688
    const int NB_N = (NN + 255) / 256;    // 391

    k_indeg<<<NB_E, 256, 0, stream>>>(dst, indeg);
    k_scan1<<<NB_N, 256, 0, stream>>>(indeg, bsum, dinv);
    k_scan2<<<1, 512, 0, stream>>>(bsum, NB_N);
    k_scan3<<<NB_N, 256, 0, stream>>>(indeg, bsum, rowstart);
    k_fill <<<NB_E, 256, 0, stream>>>(src, dst, rowstart, cursor, dinv, csr);

    const int NB_D = NN / 4;  // 25000

    // layer 1
    k_dense<IND><<<NB_D, 256, 0, stream>>>(x, W1, A);
    k_gather<<<NB_D, 256, 0, stream>>>(A, rowstart, indeg, csr, dinv, b1, B);
    // layer 2
    k_dense<HIDD><<<NB_D, 256, 0, stream>>>(B, W2, A);
    k_gather<<<NB_D, 256, 0, stream>>>(A, rowstart, indeg, csr, dinv, b2, B);
    // layer 3
    k_dense<HIDD><<<NB_D, 256, 0, stream>>>(B, W3, A);
    k_gather<<<NB_D, 256, 0, stream>>>(A, rowstart, indeg, csr, dinv, b3, B);

    k_pool<<<NB_N, 256, 0, stream>>>(B, batch, msum, mmax, cnt);

    k_cls<<<NG, 64, 0, stream>>>(msum, mmax, cnt, cw1, cb1, g1, be1,
                                 cw2, cb2, g2, be2, cw3, cb3, out);
}